// Round 18
// baseline (561.746 us; speedup 1.0000x reference)
//
#include <hip/hip_runtime.h>
#include <hip/hip_bf16.h>
#include <hip/hip_cooperative_groups.h>
#include <math.h>

namespace cg = cooperative_groups;

#define NF 50000
#define NM 5000
#define EFF 800000
#define EMF 200000

#define FB 196   // flow blocks (also #scan virtual blocks per array)
#define MB 20    // memb blocks

typedef __attribute__((ext_vector_type(8))) short s8;
typedef __attribute__((ext_vector_type(4))) float f4;

__device__ __forceinline__ short f2b(float f) {
    __hip_bfloat16 h = __float2bfloat16(f);
    return *reinterpret_cast<short*>(&h);
}

// ---- fused prep: flow-enc | memb-enc | FiLM, by blockIdx section ----
__global__ void k_prep(const float* __restrict__ flow_x, const float* __restrict__ memb_y,
                       const float* __restrict__ tau,
                       const float* __restrict__ enc_f_W, const float* __restrict__ enc_f_b,
                       const float* __restrict__ W1, const float* __restrict__ b1,
                       const float* __restrict__ W2, const float* __restrict__ b2,
                       const float* __restrict__ decW, const float* __restrict__ decb,
                       const float* __restrict__ Wk, const float* __restrict__ Wv,
                       const float* __restrict__ tcW1, const float* __restrict__ tcb1,
                       const float* __restrict__ tcW2, const float* __restrict__ tcb2,
                       float* __restrict__ xf0, float* __restrict__ knode,
                       float* __restrict__ vnode, float* __restrict__ outm,
                       float* __restrict__ misc) {
    __shared__ float sh[1200];
    const int b = blockIdx.x, tid = threadIdx.x;
    if (b < FB) {
        float* sW = sh; float* sb = sh + 304; float* st = sh + 320;
        for (int i = tid; i < 304; i += 256) sW[i] = enc_f_W[i];
        if (tid < 16) sb[tid] = enc_f_b[tid];
        if (tid < 8) {
            float fr = expf(-logf(10000.0f) * (float)tid / 8.0f);
            float a = tau[0] * fr;
            st[tid] = sinf(a);
            st[tid + 8] = cosf(a);
        }
        __syncthreads();
        int n = b * 256 + tid;
        if (n >= NF) return;
        float i0 = flow_x[n * 3], i1 = flow_x[n * 3 + 1], i2 = flow_x[n * 3 + 2];
        float f[16];
#pragma unroll
        for (int c = 0; c < 16; c++) {
            float acc = sb[c] + i0 * sW[c] + i1 * sW[16 + c] + i2 * sW[32 + c];
#pragma unroll
            for (int i = 0; i < 16; i++) acc += st[i] * sW[(3 + i) * 16 + c];
            f[c] = acc;
        }
#pragma unroll
        for (int q = 0; q < 4; q++)
            reinterpret_cast<float4*>(xf0)[n * 4 + q] =
                make_float4(f[4 * q], f[4 * q + 1], f[4 * q + 2], f[4 * q + 3]);
    } else if (b < FB + MB) {
        float* sW1 = sh;            // 304
        float* sb1 = sh + 304;      // 16
        float* sW2 = sh + 320;      // 256
        float* sb2 = sh + 576;      // 16
        float* sD  = sh + 592;      // 48
        float* sdb = sh + 640;      // 3
        float* st  = sh + 644;      // 16
        float* sWk = sh + 660;      // 256
        float* sWv = sh + 916;      // 256
        for (int i = tid; i < 304; i += 256) sW1[i] = W1[i];
        for (int i = tid; i < 256; i += 256) { sW2[i] = W2[i]; sWk[i] = Wk[i]; sWv[i] = Wv[i]; }
        if (tid < 16) { sb1[tid] = b1[tid]; sb2[tid] = b2[tid]; }
        if (tid < 48) sD[tid] = decW[tid];
        if (tid < 3) sdb[tid] = decb[tid];
        if (tid < 8) {
            float fr = expf(-logf(10000.0f) * (float)tid / 8.0f);
            float a = tau[0] * fr;
            st[tid] = sinf(a);
            st[tid + 8] = cosf(a);
        }
        __syncthreads();
        int n = (b - FB) * 256 + tid;
        if (n >= NM) return;
        float i0 = memb_y[n * 3], i1 = memb_y[n * 3 + 1], i2 = memb_y[n * 3 + 2];
        float h1[16];
#pragma unroll
        for (int c = 0; c < 16; c++) {
            float acc = sb1[c] + i0 * sW1[c] + i1 * sW1[16 + c] + i2 * sW1[32 + c];
#pragma unroll
            for (int i = 0; i < 16; i++) acc += st[i] * sW1[(3 + i) * 16 + c];
            h1[c] = fmaxf(acc, 0.f);
        }
        float xm[16];
#pragma unroll
        for (int c = 0; c < 16; c++) {
            float acc = sb2[c];
#pragma unroll
            for (int i = 0; i < 16; i++) acc += h1[i] * sW2[i * 16 + c];
            xm[c] = fmaxf(acc, 0.f);
        }
        float kn[16], vn[16];
#pragma unroll
        for (int c = 0; c < 16; c++) {
            float ak = 0.f, av = 0.f;
#pragma unroll
            for (int i = 0; i < 16; i++) { ak += xm[i] * sWk[i * 16 + c]; av += xm[i] * sWv[i * 16 + c]; }
            kn[c] = ak; vn[c] = av;
        }
#pragma unroll
        for (int q = 0; q < 4; q++) {
            reinterpret_cast<float4*>(knode)[n * 4 + q] =
                make_float4(kn[4 * q], kn[4 * q + 1], kn[4 * q + 2], kn[4 * q + 3]);
            reinterpret_cast<float4*>(vnode)[n * 4 + q] =
                make_float4(vn[4 * q], vn[4 * q + 1], vn[4 * q + 2], vn[4 * q + 3]);
        }
#pragma unroll
        for (int k = 0; k < 3; k++) {
            float acc = sdb[k];
#pragma unroll
            for (int i = 0; i < 16; i++) acc += xm[i] * sD[i * 3 + k];
            outm[n * 3 + k] = acc;
        }
    } else {
        float* temb = sh; float* h = sh + 16;
        if (tid < 8) {
            float fr = expf(-logf(10000.0f) * (float)tid / 8.0f);
            float a = tau[0] * fr;
            temb[tid] = sinf(a);
            temb[tid + 8] = cosf(a);
        }
        __syncthreads();
        if (tid < 16) {
            float acc = tcb1[tid];
#pragma unroll
            for (int i = 0; i < 16; i++) acc += temb[i] * tcW1[i * 16 + tid];
            h[tid] = fmaxf(acc, 0.f);
            misc[tid] = temb[tid];
        }
        __syncthreads();
        if (tid < 32) {
            float acc = tcb2[tid];
#pragma unroll
            for (int i = 0; i < 16; i++) acc += h[i] * tcW2[i * 32 + tid];
            misc[16 + tid] = acc;   // misc[16..31]=scale, misc[32..47]=shift
        }
    }
}

// ---- cooperative CSR build: hist -> sync -> block sums -> sync -> offsets
//      -> sync -> scatter. One launch replaces four. ----
__global__ void k_graph(const int* __restrict__ dst_ff, const int* __restrict__ dst_mf,
                        int* __restrict__ cnt, int* __restrict__ cnt2,
                        int* __restrict__ bsA, int* __restrict__ bsB,
                        int* __restrict__ base, int* __restrict__ base2,
                        int* __restrict__ eidxp, int* __restrict__ eidx2) {
    cg::grid_group grid = cg::this_grid();
    __shared__ int s0[256], s1[256];
    const int tid = threadIdx.x, b = blockIdx.x;
    const int gsz = gridDim.x * 256;
    // phase A: histograms
    for (int gid = b * 256 + tid; gid < EFF + EMF; gid += gsz) {
        if (gid < EFF) atomicAdd(&cnt[dst_ff[gid]], 1);
        else atomicAdd(&cnt2[dst_mf[gid - EFF]], 1);
    }
    grid.sync();
    // phase B: per-block sums (2*FB virtual blocks)
    if (b < 2 * FB) {
        int which = b >= FB;
        const int* c = which ? cnt2 : cnt;
        int* bs = which ? bsB : bsA;
        int vb = b - (which ? FB : 0);
        int n = vb * 256 + tid;
        s0[tid] = (n < NF) ? c[n] : 0;
        __syncthreads();
        for (int s = 128; s > 0; s >>= 1) { if (tid < s) s0[tid] += s0[tid + s]; __syncthreads(); }
        if (tid == 0) bs[vb] = s0[0];
    }
    grid.sync();
    // phase C: start offsets
    if (b < 2 * FB) {
        int which = b >= FB;
        const int* cArr = which ? cnt2 : cnt;
        const int* bs = which ? bsB : bsA;
        int* outb = which ? base2 : base;
        int vb = b - (which ? FB : 0);
        int n = vb * 256 + tid;
        s0[tid] = (tid < vb) ? bs[tid] : 0;
        __syncthreads();
        for (int s = 128; s > 0; s >>= 1) { if (tid < s) s0[tid] += s0[tid + s]; __syncthreads(); }
        int off0 = s0[0];
        __syncthreads();
        int c = (n < NF) ? cArr[n] : 0;
        s0[tid] = c;
        __syncthreads();
        int* cur = s0; int* nxt = s1;
        for (int s = 1; s < 256; s <<= 1) {
            nxt[tid] = cur[tid] + ((tid >= s) ? cur[tid - s] : 0);
            __syncthreads();
            int* tmp = cur; cur = nxt; nxt = tmp;
        }
        int excl = cur[tid] - c;
        if (n < NF) outb[n] = off0 + excl;
    }
    grid.sync();
    // phase D: scatter edge ids (base arrays become end-cursors)
    for (int gid = b * 256 + tid; gid < EFF + EMF; gid += gsz) {
        if (gid < EFF) {
            int d = dst_ff[gid];
            int pos = atomicAdd(&base[d], 1);
            eidxp[pos] = gid;
        } else {
            int e = gid - EFF;
            int d = dst_mf[e];
            int pos = atomicAdd(&base2[d], 1);
            eidx2[pos] = e;
        }
    }
}

// ---- Phase E1: fused NNConv edge kernel, DUAL-CHAIN ILP (r17, ~98 us) ----
__global__ void __launch_bounds__(256, 1) k_edge_msg(
        const float* __restrict__ ea, const int* __restrict__ src,
        const float* __restrict__ K0, const float* __restrict__ kb0,
        const float* __restrict__ K1, const float* __restrict__ kb1,
        const float* __restrict__ K2, const float* __restrict__ kb2,
        const float* __restrict__ xf0, float* __restrict__ msgbuf,
        int e0, int nbt) {
    __shared__ __align__(16) char smem_big[32768];
    __shared__ __align__(16) float sK0[384];
    __shared__ __align__(16) float skb0[64];
    __shared__ __align__(16) float sb2[256];
    __shared__ __align__(16) short kh1buf[4][1024];
    __shared__ __align__(16) float pbuf[4][1024];

    const int tid = threadIdx.x;
    const int w = tid >> 6, lane = tid & 63;
    const int cl = lane & 15, g = lane >> 4;

    float* sK1 = (float*)smem_big;
    short* fragK2 = (short*)smem_big;
    for (int i = tid; i < 4096; i += 256) sK1[i] = K1[i];
    for (int i = tid; i < 384; i += 256) sK0[i] = K0[i];
    if (tid < 64) skb0[tid] = kb0[tid];
    if (tid < 256) sb2[tid] = kb2[tid];
    __syncthreads();
    s8 K1B[2][4];
#pragma unroll
    for (int s = 0; s < 2; s++)
#pragma unroll
        for (int n = 0; n < 4; n++) {
            s8 v;
#pragma unroll
            for (int jj = 0; jj < 8; jj++)
                v[jj] = f2b(sK1[(32 * s + 8 * g + jj) * 64 + 16 * n + cl]);
            K1B[s][n] = v;
        }
    float b1v[4];
#pragma unroll
    for (int n = 0; n < 4; n++) b1v[n] = kb1[16 * n + cl];
    __syncthreads();
    for (int idx = tid; idx < 16384; idx += 256) {
        int n = idx >> 10, s = (idx >> 9) & 1, l2 = (idx >> 3) & 63, jj = idx & 7;
        fragK2[idx] = f2b(K2[(32 * s + 8 * (l2 >> 4) + jj) * 256 + 16 * n + (l2 & 15)]);
    }
    __syncthreads();

    const f4* K04 = (const f4*)sK0;
    const f4* KB04 = (const f4*)skb0;
    short* kh1w = kh1buf[w];
    float* pw = pbuf[w];
    const s8* K2f = (const s8*)fragK2;

    const int half = nbt >> 1;
    int gb = blockIdx.x;
    if (gb >= half) return;
    float pe[2][6]; int psi[2];
#pragma unroll
    for (int c = 0; c < 2; c++) {
        const int te = e0 + (gb + c * half) * 64 + w * 16 + cl;
        const float2* ep2 = reinterpret_cast<const float2*>(ea + (size_t)te * 6);
        float2 a = ep2[0], b = ep2[1], cc = ep2[2];
        pe[c][0] = a.x; pe[c][1] = a.y; pe[c][2] = b.x;
        pe[c][3] = b.y; pe[c][4] = cc.x; pe[c][5] = cc.y;
        psi[c] = src[te];
    }

    for (; gb < half; gb += gridDim.x) {
        int eb2[2];
        eb2[0] = gb * 64 + w * 16;
        eb2[1] = (gb + half) * 64 + w * 16;
        f4 xq2[2];
        float ce[2][6];
#pragma unroll
        for (int c = 0; c < 2; c++) {
            xq2[c] = *(const f4*)(xf0 + (size_t)psi[c] * 16 + g * 4);
#pragma unroll
            for (int k = 0; k < 6; k++) ce[c][k] = pe[c][k];
        }
        {
            int gn = gb + gridDim.x;
            if (gn > half - 1) gn = half - 1;
#pragma unroll
            for (int c = 0; c < 2; c++) {
                const int ten = e0 + (gn + c * half) * 64 + w * 16 + cl;
                const float2* ep2 = reinterpret_cast<const float2*>(ea + (size_t)ten * 6);
                float2 a = ep2[0], b = ep2[1], cc = ep2[2];
                pe[c][0] = a.x; pe[c][1] = a.y; pe[c][2] = b.x;
                pe[c][3] = b.y; pe[c][4] = cc.x; pe[c][5] = cc.y;
                psi[c] = src[ten];
            }
        }

        s8 a3s[2][2];
#pragma unroll
        for (int c = 0; c < 2; c++) {
            s8 a1[2];
#pragma unroll
            for (int s = 0; s < 2; s++) {
                f4 accA = KB04[8 * s + 2 * g];
                f4 accB = KB04[8 * s + 2 * g + 1];
#pragma unroll
                for (int f = 0; f < 6; f++) {
                    accA += ce[c][f] * K04[f * 16 + 8 * s + 2 * g];
                    accB += ce[c][f] * K04[f * 16 + 8 * s + 2 * g + 1];
                }
                s8 v;
#pragma unroll
                for (int jj = 0; jj < 4; jj++) v[jj] = f2b(fmaxf(accA[jj], 0.f));
#pragma unroll
                for (int jj = 0; jj < 4; jj++) v[4 + jj] = f2b(fmaxf(accB[jj], 0.f));
                a1[s] = v;
            }
#pragma unroll
            for (int n = 0; n < 4; n++) {
                f4 c2 = {0.f, 0.f, 0.f, 0.f};
                c2 = __builtin_amdgcn_mfma_f32_16x16x32_bf16(a1[0], K1B[0][n], c2, 0, 0, 0);
                c2 = __builtin_amdgcn_mfma_f32_16x16x32_bf16(a1[1], K1B[1][n], c2, 0, 0, 0);
#pragma unroll
                for (int r = 0; r < 4; r++) {
                    const int e = 4 * g + r;
                    const int byteoff = (e * 128 + (16 * n + cl) * 2) ^ ((e & 7) << 4);
                    *(short*)((char*)kh1w + byteoff) = f2b(fmaxf(c2[r] + b1v[n], 0.f));
                }
            }
#pragma unroll
            for (int s = 0; s < 2; s++) {
                const int byteoff = (cl * 128 + 64 * s + 16 * g) ^ ((cl & 7) << 4);
                a3s[c][s] = *(const s8*)((const char*)kh1w + byteoff);
            }
        }

#pragma unroll
        for (int c = 0; c < 2; c++) {
            f4 pv4;
#pragma unroll
            for (int n = 0; n < 16; n++) {
                f4 acc = *(const f4*)(sb2 + 16 * n + 4 * g);
                acc = __builtin_amdgcn_mfma_f32_16x16x32_bf16(K2f[(2 * n + 0) * 64 + lane], a3s[c][0], acc, 0, 0, 0);
                acc = __builtin_amdgcn_mfma_f32_16x16x32_bf16(K2f[(2 * n + 1) * 64 + lane], a3s[c][1], acc, 0, 0, 0);
                pv4[n & 3] = acc[0] * xq2[c][0] + acc[1] * xq2[c][1]
                           + acc[2] * xq2[c][2] + acc[3] * xq2[c][3];
                if ((n & 3) == 3) {
                    const int byteoff = (g * 1024 + cl * 64 + (n >> 2) * 16) ^ ((cl & 7) << 4);
                    *(f4*)((char*)pw + byteoff) = pv4;
                }
            }
            const int e16 = lane >> 2, q = lane & 3;
            f4 s0 = {0.f, 0.f, 0.f, 0.f};
#pragma unroll
            for (int gg = 0; gg < 4; gg++) {
                const int byteoff = (gg * 1024 + e16 * 64 + q * 16) ^ ((e16 & 7) << 4);
                f4 t = *(const f4*)((const char*)pw + byteoff);
                s0[0] += t[0]; s0[1] += t[1]; s0[2] += t[2]; s0[3] += t[3];
            }
            reinterpret_cast<f4*>(msgbuf)[(size_t)eb2[c] * 4 + lane] = s0;
        }
    }
}

// ---- Phase E2 (two-pass fallback only): segmented CSR reduction -> agg ----
__global__ void k_reduce(const float* __restrict__ msgbuf, const int* __restrict__ eidxp,
                         const int* __restrict__ basec, const int* __restrict__ cnt,
                         float* __restrict__ agg, int e0, int e1, int first) {
    int n = blockIdx.x * 256 + threadIdx.x;
    if (n >= NF) return;
    int c = cnt[n];
    int st = basec[n] - c;
    f4 a0, a1, a2, a3;
    if (first) {
        a0 = a1 = a2 = a3 = (f4){0.f, 0.f, 0.f, 0.f};
    } else {
        const f4* ap = (const f4*)(agg + (size_t)n * 16);
        a0 = ap[0]; a1 = ap[1]; a2 = ap[2]; a3 = ap[3];
    }
    for (int j = 0; j < c; j++) {
        int eid = eidxp[st + j];
        if (eid < e0 || eid >= e1) continue;
        const f4* mp = (const f4*)(msgbuf + (size_t)(eid - e0) * 16);
        a0 += mp[0]; a1 += mp[1]; a2 += mp[2]; a3 += mp[3];
    }
    f4* op = (f4*)(agg + (size_t)n * 16);
    op[0] = a0; op[1] = a1; op[2] = a2; op[3] = a3;
}

// ---- Phase F: fused msg reduce + root + online-softmax attention + FiLM + dec ----
__global__ void __launch_bounds__(256, 1) k_final(
        const float* __restrict__ xf0, const float* __restrict__ agg,
        const float* __restrict__ msgbuf, const int* __restrict__ eidxp,
        const int* __restrict__ basec,
        const int* __restrict__ cnt, const int* __restrict__ cnt2,
        const int* __restrict__ base2c, const int* __restrict__ eidx2,
        const int* __restrict__ src_mf, const float* __restrict__ ea,
        const float* __restrict__ knode, const float* __restrict__ vnode,
        const float* __restrict__ misc,
        const float* __restrict__ Wq, const float* __restrict__ We,
        const float* __restrict__ Wr, const float* __restrict__ br,
        const float* __restrict__ dW, const float* __restrict__ db,
        float* __restrict__ out, int fuseReduce) {
    __shared__ float sWr[256], sWq[256], sWe[96], sbr[16], ssc[16], ssh[16], sD[48], sdb[3];
    int tid = threadIdx.x;
    for (int i = tid; i < 256; i += 256) { sWr[i] = Wr[i]; sWq[i] = Wq[i]; }
    if (tid < 96) sWe[tid] = We[tid];
    if (tid < 16) { sbr[tid] = br[tid]; ssc[tid] = misc[16 + tid]; ssh[tid] = misc[32 + tid]; }
    if (tid < 48) sD[tid] = dW[tid];
    if (tid < 3) sdb[tid] = db[tid];
    __syncthreads();
    int n = blockIdx.x * 256 + tid;
    if (n >= NF) return;
    int c = cnt[n];
    f4 a0, a1, a2, a3;
    if (fuseReduce) {
        a0 = a1 = a2 = a3 = (f4){0.f, 0.f, 0.f, 0.f};
        int st = basec[n] - c;
        if (c > 0) {
            int eid = eidxp[st];
            for (int j = 0; j < c; j++) {
                int eidn = eid;
                if (j + 1 < c) eidn = eidxp[st + j + 1];
                const f4* mp = (const f4*)(msgbuf + (size_t)eid * 16);
                a0 += mp[0]; a1 += mp[1]; a2 += mp[2]; a3 += mp[3];
                eid = eidn;
            }
        }
    } else {
        const f4* ap = (const f4*)(agg + (size_t)n * 16);
        a0 = ap[0]; a1 = ap[1]; a2 = ap[2]; a3 = ap[3];
    }
    float f[16];
#pragma unroll
    for (int q = 0; q < 4; q++) {
        float4 v = reinterpret_cast<const float4*>(xf0)[n * 4 + q];
        f[4 * q] = v.x; f[4 * q + 1] = v.y; f[4 * q + 2] = v.z; f[4 * q + 3] = v.w;
    }
    float r[16], qv[16];
#pragma unroll
    for (int cc = 0; cc < 16; cc++) {
        float ar = sbr[cc], aq = 0.f;
#pragma unroll
        for (int i = 0; i < 16; i++) { ar += f[i] * sWr[i * 16 + cc]; aq += f[i] * sWq[i * 16 + cc]; }
        r[cc] = ar; qv[cc] = aq;
    }
    float num[16];
#pragma unroll
    for (int i = 0; i < 16; i++) num[i] = 0.f;
    float den = 0.f, m = -3.0e38f;
    int c2 = cnt2[n];
    int st2 = base2c[n] - c2;
    if (c2 > 0) {
        int eid = eidx2[st2];
        int s = src_mf[eid];
        for (int j = 0; j < c2; j++) {
            int eidn = eid, sn = s;
            if (j + 1 < c2) { eidn = eidx2[st2 + j + 1]; sn = src_mf[eidn]; }
            const float2* ep = reinterpret_cast<const float2*>(ea + (size_t)eid * 6);
            float2 e01 = ep[0], e23 = ep[1], e45 = ep[2];
            float sc = 0.f;
#pragma unroll
            for (int q4i = 0; q4i < 4; q4i++) {
                float4 k4 = reinterpret_cast<const float4*>(knode)[(size_t)s * 4 + q4i];
                float kk[4] = {k4.x, k4.y, k4.z, k4.w};
#pragma unroll
                for (int jj = 0; jj < 4; jj++) {
                    int cc = 4 * q4i + jj;
                    kk[jj] += e01.x * sWe[cc] + e01.y * sWe[16 + cc] + e23.x * sWe[32 + cc]
                            + e23.y * sWe[48 + cc] + e45.x * sWe[64 + cc] + e45.y * sWe[80 + cc];
                    sc += qv[cc] * kk[jj];
                }
            }
            sc *= 0.25f;
            if (sc > m) {
                float rs = expf(m - sc);
                den *= rs;
#pragma unroll
                for (int i = 0; i < 16; i++) num[i] *= rs;
                m = sc;
            }
            float e = expf(sc - m);
            den += e;
#pragma unroll
            for (int q4i = 0; q4i < 4; q4i++) {
                float4 v4 = reinterpret_cast<const float4*>(vnode)[(size_t)s * 4 + q4i];
                num[4 * q4i + 0] += e * v4.x;
                num[4 * q4i + 1] += e * v4.y;
                num[4 * q4i + 2] += e * v4.z;
                num[4 * q4i + 3] += e * v4.w;
            }
            eid = eidn; s = sn;
        }
    }
    float rdn = 1.0f / (den + 1e-16f);
    float rdg = 1.0f / fmaxf((float)c, 1.0f);
    float xo[16];
#pragma unroll
    for (int q = 0; q < 4; q++) {
        f4 a4 = (q == 0) ? a0 : (q == 1) ? a1 : (q == 2) ? a2 : a3;
#pragma unroll
        for (int jj = 0; jj < 4; jj++) {
            int cc = 4 * q + jj;
            float v = r[cc] + a4[jj] * rdg + num[cc] * rdn;
            float rr = fmaxf(v, 0.f);
            xo[cc] = rr + (rr * ssc[cc] + ssh[cc]);
        }
    }
#pragma unroll
    for (int k = 0; k < 3; k++) {
        float acc = sdb[k];
#pragma unroll
        for (int i = 0; i < 16; i++) acc += xo[i] * sD[i * 3 + k];
        out[n * 3 + k] = acc;
    }
}

extern "C" void kernel_launch(void* const* d_in, const int* in_sizes, int n_in,
                              void* d_out, int out_size, void* d_ws, size_t ws_size,
                              hipStream_t stream) {
    const float* flow_x   = (const float*)d_in[0];
    const float* memb_y   = (const float*)d_in[1];
    const float* tau      = (const float*)d_in[2];
    const float* ea_ff    = (const float*)d_in[3];
    const float* ea_mf    = (const float*)d_in[4];
    const float* enc_f_W  = (const float*)d_in[5];
    const float* enc_f_b  = (const float*)d_in[6];
    const float* enc_m_W1 = (const float*)d_in[7];
    const float* enc_m_b1 = (const float*)d_in[8];
    const float* enc_m_W2 = (const float*)d_in[9];
    const float* enc_m_b2 = (const float*)d_in[10];
    const float* K0       = (const float*)d_in[11];
    const float* kb0      = (const float*)d_in[12];
    const float* K1       = (const float*)d_in[13];
    const float* kb1      = (const float*)d_in[14];
    const float* K2       = (const float*)d_in[15];
    const float* kb2      = (const float*)d_in[16];
    const float* W_root   = (const float*)d_in[17];
    const float* b_root   = (const float*)d_in[18];
    const float* Wq       = (const float*)d_in[19];
    const float* Wk       = (const float*)d_in[20];
    const float* We       = (const float*)d_in[21];
    const float* Wv       = (const float*)d_in[22];
    const float* tc_W1    = (const float*)d_in[23];
    const float* tc_b1    = (const float*)d_in[24];
    const float* tc_W2    = (const float*)d_in[25];
    const float* tc_b2    = (const float*)d_in[26];
    const float* dec_f_W  = (const float*)d_in[27];
    const float* dec_f_b  = (const float*)d_in[28];
    const float* dec_m_W  = (const float*)d_in[29];
    const float* dec_m_b  = (const float*)d_in[30];
    const int* src_ff = (const int*)d_in[31];
    const int* dst_ff = (const int*)d_in[32];
    const int* src_mf = (const int*)d_in[33];
    const int* dst_mf = (const int*)d_in[34];

    float* out = (float*)d_out;
    float* ws = (float*)d_ws;

    // fixed region: 2,960,576 elems = 11.84 MB
    float* misc  = ws;                           // 64
    float* knode = ws + 64;                      // NM*16
    float* vnode = knode + (size_t)NM * 16;      // NM*16
    float* xf0   = vnode + (size_t)NM * 16;      // NF*16
    float* agg   = xf0 + (size_t)NF * 16;        // NF*16 (two-pass fallback only)
    int* cnt    = (int*)(agg + (size_t)NF * 16); // NF    (zeroed)
    int* cnt2   = cnt + NF;                      // NF    (zeroed)
    int* base   = cnt2 + NF;                     // NF
    int* base2  = base + NF;                     // NF
    int* eidxp  = base2 + NF;                    // EFF
    int* eidx2  = eidxp + EFF;                   // EMF
    int* bsA    = eidx2 + EMF;                   // 256
    int* bsB    = bsA + 256;                     // 256
    float* msgbuf = (float*)(bsB + 256);         // EH*16 floats

    const int npass = (ws_size >= 63100000ULL) ? 1 : 2;
    const int EH = EFF / npass;

    hipMemsetAsync(cnt, 0, 2 * (size_t)NF * sizeof(int), stream);

    k_prep<<<FB + MB + 1, 256, 0, stream>>>(
        flow_x, memb_y, tau, enc_f_W, enc_f_b, enc_m_W1, enc_m_b1, enc_m_W2, enc_m_b2,
        dec_m_W, dec_m_b, Wk, Wv, tc_W1, tc_b1, tc_W2, tc_b2,
        xf0, knode, vnode, out + (size_t)NF * 3, misc);
    {
        void* kargs[] = { (void*)&dst_ff, (void*)&dst_mf, (void*)&cnt, (void*)&cnt2,
                          (void*)&bsA, (void*)&bsB, (void*)&base, (void*)&base2,
                          (void*)&eidxp, (void*)&eidx2 };
        hipLaunchCooperativeKernel((const void*)k_graph, dim3(1024), dim3(256),
                                   kargs, 0, stream);
    }
    if (npass == 1) {
        k_edge_msg<<<512, 256, 0, stream>>>(ea_ff, src_ff, K0, kb0, K1, kb1, K2, kb2,
                                            xf0, msgbuf, 0, EFF / 64);
        k_final<<<FB, 256, 0, stream>>>(xf0, agg, msgbuf, eidxp, base, cnt, cnt2,
                                        base2, eidx2, src_mf, ea_mf, knode, vnode, misc,
                                        Wq, We, W_root, b_root, dec_f_W, dec_f_b, out, 1);
    } else {
        for (int p = 0; p < npass; p++) {
            k_edge_msg<<<512, 256, 0, stream>>>(ea_ff, src_ff, K0, kb0, K1, kb1, K2, kb2,
                                                xf0, msgbuf, p * EH, EH / 64);
            k_reduce<<<FB, 256, 0, stream>>>(msgbuf, eidxp, base, cnt, agg,
                                             p * EH, (p + 1) * EH, p == 0);
        }
        k_final<<<FB, 256, 0, stream>>>(xf0, agg, msgbuf, eidxp, base, cnt, cnt2,
                                        base2, eidx2, src_mf, ea_mf, knode, vnode, misc,
                                        Wq, We, W_root, b_root, dec_f_W, dec_f_b, out, 0);
    }
}

// Round 19
// 258.961 us; speedup vs baseline: 2.1692x; 2.1692x over previous
//
#include <hip/hip_runtime.h>
#include <hip/hip_bf16.h>
#include <math.h>

#define NF 50000
#define NM 5000
#define EFF 800000
#define EMF 200000

#define FB 196   // flow blocks
#define MB 20    // memb blocks
#define HB 3907  // hist blocks ((EFF+EMF+255)/256)

typedef __attribute__((ext_vector_type(8))) short s8;
typedef __attribute__((ext_vector_type(4))) float f4;

__device__ __forceinline__ short f2b(float f) {
    __hip_bfloat16 h = __float2bfloat16(f);
    return *reinterpret_cast<short*>(&h);
}

// ---- fused prep: flow-enc | memb-enc | FiLM | histograms, by blockIdx section ----
__global__ void k_prep(const float* __restrict__ flow_x, const float* __restrict__ memb_y,
                       const float* __restrict__ tau,
                       const float* __restrict__ enc_f_W, const float* __restrict__ enc_f_b,
                       const float* __restrict__ W1, const float* __restrict__ b1,
                       const float* __restrict__ W2, const float* __restrict__ b2,
                       const float* __restrict__ decW, const float* __restrict__ decb,
                       const float* __restrict__ Wk, const float* __restrict__ Wv,
                       const float* __restrict__ tcW1, const float* __restrict__ tcb1,
                       const float* __restrict__ tcW2, const float* __restrict__ tcb2,
                       const int* __restrict__ dst_ff, const int* __restrict__ dst_mf,
                       float* __restrict__ xf0, float* __restrict__ knode,
                       float* __restrict__ vnode, float* __restrict__ outm,
                       float* __restrict__ misc, int* __restrict__ cnt,
                       int* __restrict__ cnt2) {
    __shared__ float sh[1200];
    const int b = blockIdx.x, tid = threadIdx.x;
    if (b < FB) {
        float* sW = sh; float* sb = sh + 304; float* st = sh + 320;
        for (int i = tid; i < 304; i += 256) sW[i] = enc_f_W[i];
        if (tid < 16) sb[tid] = enc_f_b[tid];
        if (tid < 8) {
            float fr = expf(-logf(10000.0f) * (float)tid / 8.0f);
            float a = tau[0] * fr;
            st[tid] = sinf(a);
            st[tid + 8] = cosf(a);
        }
        __syncthreads();
        int n = b * 256 + tid;
        if (n >= NF) return;
        float i0 = flow_x[n * 3], i1 = flow_x[n * 3 + 1], i2 = flow_x[n * 3 + 2];
        float f[16];
#pragma unroll
        for (int c = 0; c < 16; c++) {
            float acc = sb[c] + i0 * sW[c] + i1 * sW[16 + c] + i2 * sW[32 + c];
#pragma unroll
            for (int i = 0; i < 16; i++) acc += st[i] * sW[(3 + i) * 16 + c];
            f[c] = acc;
        }
#pragma unroll
        for (int q = 0; q < 4; q++)
            reinterpret_cast<float4*>(xf0)[n * 4 + q] =
                make_float4(f[4 * q], f[4 * q + 1], f[4 * q + 2], f[4 * q + 3]);
    } else if (b < FB + MB) {
        float* sW1 = sh;            // 304
        float* sb1 = sh + 304;      // 16
        float* sW2 = sh + 320;      // 256
        float* sb2 = sh + 576;      // 16
        float* sD  = sh + 592;      // 48
        float* sdb = sh + 640;      // 3
        float* st  = sh + 644;      // 16
        float* sWk = sh + 660;      // 256
        float* sWv = sh + 916;      // 256
        for (int i = tid; i < 304; i += 256) sW1[i] = W1[i];
        for (int i = tid; i < 256; i += 256) { sW2[i] = W2[i]; sWk[i] = Wk[i]; sWv[i] = Wv[i]; }
        if (tid < 16) { sb1[tid] = b1[tid]; sb2[tid] = b2[tid]; }
        if (tid < 48) sD[tid] = decW[tid];
        if (tid < 3) sdb[tid] = decb[tid];
        if (tid < 8) {
            float fr = expf(-logf(10000.0f) * (float)tid / 8.0f);
            float a = tau[0] * fr;
            st[tid] = sinf(a);
            st[tid + 8] = cosf(a);
        }
        __syncthreads();
        int n = (b - FB) * 256 + tid;
        if (n >= NM) return;
        float i0 = memb_y[n * 3], i1 = memb_y[n * 3 + 1], i2 = memb_y[n * 3 + 2];
        float h1[16];
#pragma unroll
        for (int c = 0; c < 16; c++) {
            float acc = sb1[c] + i0 * sW1[c] + i1 * sW1[16 + c] + i2 * sW1[32 + c];
#pragma unroll
            for (int i = 0; i < 16; i++) acc += st[i] * sW1[(3 + i) * 16 + c];
            h1[c] = fmaxf(acc, 0.f);
        }
        float xm[16];
#pragma unroll
        for (int c = 0; c < 16; c++) {
            float acc = sb2[c];
#pragma unroll
            for (int i = 0; i < 16; i++) acc += h1[i] * sW2[i * 16 + c];
            xm[c] = fmaxf(acc, 0.f);
        }
        float kn[16], vn[16];
#pragma unroll
        for (int c = 0; c < 16; c++) {
            float ak = 0.f, av = 0.f;
#pragma unroll
            for (int i = 0; i < 16; i++) { ak += xm[i] * sWk[i * 16 + c]; av += xm[i] * sWv[i * 16 + c]; }
            kn[c] = ak; vn[c] = av;
        }
#pragma unroll
        for (int q = 0; q < 4; q++) {
            reinterpret_cast<float4*>(knode)[n * 4 + q] =
                make_float4(kn[4 * q], kn[4 * q + 1], kn[4 * q + 2], kn[4 * q + 3]);
            reinterpret_cast<float4*>(vnode)[n * 4 + q] =
                make_float4(vn[4 * q], vn[4 * q + 1], vn[4 * q + 2], vn[4 * q + 3]);
        }
#pragma unroll
        for (int k = 0; k < 3; k++) {
            float acc = sdb[k];
#pragma unroll
            for (int i = 0; i < 16; i++) acc += xm[i] * sD[i * 3 + k];
            outm[n * 3 + k] = acc;
        }
    } else if (b == FB + MB) {
        float* temb = sh; float* h = sh + 16;
        if (tid < 8) {
            float fr = expf(-logf(10000.0f) * (float)tid / 8.0f);
            float a = tau[0] * fr;
            temb[tid] = sinf(a);
            temb[tid + 8] = cosf(a);
        }
        __syncthreads();
        if (tid < 16) {
            float acc = tcb1[tid];
#pragma unroll
            for (int i = 0; i < 16; i++) acc += temb[i] * tcW1[i * 16 + tid];
            h[tid] = fmaxf(acc, 0.f);
            misc[tid] = temb[tid];
        }
        __syncthreads();
        if (tid < 32) {
            float acc = tcb2[tid];
#pragma unroll
            for (int i = 0; i < 16; i++) acc += h[i] * tcW2[i * 32 + tid];
            misc[16 + tid] = acc;   // misc[16..31]=scale, misc[32..47]=shift
        }
    } else {
        int gid = (b - FB - MB - 1) * 256 + tid;
        if (gid < EFF) {
            atomicAdd(&cnt[dst_ff[gid]], 1);
        } else if (gid < EFF + EMF) {
            atomicAdd(&cnt2[dst_mf[gid - EFF]], 1);
        }
    }
}

// ---- CSR build: per-block sums for both count arrays ----
__global__ void k_scanA2(const int* __restrict__ cnt, const int* __restrict__ cnt2,
                         int* __restrict__ bsA, int* __restrict__ bsB) {
    __shared__ int red[256];
    int which = blockIdx.x >= FB;
    const int* c = which ? cnt2 : cnt;
    int* bs = which ? bsB : bsA;
    int b = blockIdx.x - (which ? FB : 0);
    int t = threadIdx.x, n = b * 256 + t;
    red[t] = (n < NF) ? c[n] : 0;
    __syncthreads();
    for (int s = 128; s > 0; s >>= 1) { if (t < s) red[t] += red[t + s]; __syncthreads(); }
    if (t == 0) bs[b] = red[0];
}

// ---- CSR build: start offsets for both arrays ----
__global__ void k_scanC2(const int* __restrict__ cnt, const int* __restrict__ cnt2,
                         const int* __restrict__ bsA, const int* __restrict__ bsB,
                         int* __restrict__ base, int* __restrict__ base2) {
    __shared__ int s0[256], s1[256];
    int which = blockIdx.x >= FB;
    const int* cArr = which ? cnt2 : cnt;
    const int* bs = which ? bsB : bsA;
    int* outb = which ? base2 : base;
    int b = blockIdx.x - (which ? FB : 0);
    int t = threadIdx.x, n = b * 256 + t;
    s0[t] = (t < b) ? bs[t] : 0;
    __syncthreads();
    for (int s = 128; s > 0; s >>= 1) { if (t < s) s0[t] += s0[t + s]; __syncthreads(); }
    int off0 = s0[0];
    __syncthreads();
    int c = (n < NF) ? cArr[n] : 0;
    s0[t] = c;
    __syncthreads();
    int* cur = s0; int* nxt = s1;
    for (int s = 1; s < 256; s <<= 1) {
        nxt[t] = cur[t] + ((t >= s) ? cur[t - s] : 0);
        __syncthreads();
        int* tmp = cur; cur = nxt; nxt = tmp;
    }
    int excl = cur[t] - c;
    if (n < NF) outb[n] = off0 + excl;
}

// ---- CSR build: scatter edge ids (base arrays become end-cursors) ----
__global__ void k_scatter(const int* __restrict__ dst_ff, const int* __restrict__ dst_mf,
                          int* __restrict__ baseff, int* __restrict__ basemf,
                          int* __restrict__ eidxp, int* __restrict__ eidx2) {
    int gid = blockIdx.x * 256 + threadIdx.x;
    if (gid < EFF) {
        int d = dst_ff[gid];
        int pos = atomicAdd(&baseff[d], 1);
        eidxp[pos] = gid;
    } else if (gid < EFF + EMF) {
        int e = gid - EFF;
        int d = dst_mf[e];
        int pos = atomicAdd(&basemf[d], 1);
        eidx2[pos] = e;
    }
}

// ---- Phase E1: fused NNConv edge kernel, DUAL-CHAIN ILP (r17, ~98 us) ----
__global__ void __launch_bounds__(256, 1) k_edge_msg(
        const float* __restrict__ ea, const int* __restrict__ src,
        const float* __restrict__ K0, const float* __restrict__ kb0,
        const float* __restrict__ K1, const float* __restrict__ kb1,
        const float* __restrict__ K2, const float* __restrict__ kb2,
        const float* __restrict__ xf0, float* __restrict__ msgbuf,
        int e0, int nbt) {
    __shared__ __align__(16) char smem_big[32768];
    __shared__ __align__(16) float sK0[384];
    __shared__ __align__(16) float skb0[64];
    __shared__ __align__(16) float sb2[256];
    __shared__ __align__(16) short kh1buf[4][1024];
    __shared__ __align__(16) float pbuf[4][1024];

    const int tid = threadIdx.x;
    const int w = tid >> 6, lane = tid & 63;
    const int cl = lane & 15, g = lane >> 4;

    float* sK1 = (float*)smem_big;
    short* fragK2 = (short*)smem_big;
    for (int i = tid; i < 4096; i += 256) sK1[i] = K1[i];
    for (int i = tid; i < 384; i += 256) sK0[i] = K0[i];
    if (tid < 64) skb0[tid] = kb0[tid];
    if (tid < 256) sb2[tid] = kb2[tid];
    __syncthreads();
    s8 K1B[2][4];
#pragma unroll
    for (int s = 0; s < 2; s++)
#pragma unroll
        for (int n = 0; n < 4; n++) {
            s8 v;
#pragma unroll
            for (int jj = 0; jj < 8; jj++)
                v[jj] = f2b(sK1[(32 * s + 8 * g + jj) * 64 + 16 * n + cl]);
            K1B[s][n] = v;
        }
    float b1v[4];
#pragma unroll
    for (int n = 0; n < 4; n++) b1v[n] = kb1[16 * n + cl];
    __syncthreads();
    for (int idx = tid; idx < 16384; idx += 256) {
        int n = idx >> 10, s = (idx >> 9) & 1, l2 = (idx >> 3) & 63, jj = idx & 7;
        fragK2[idx] = f2b(K2[(32 * s + 8 * (l2 >> 4) + jj) * 256 + 16 * n + (l2 & 15)]);
    }
    __syncthreads();

    const f4* K04 = (const f4*)sK0;
    const f4* KB04 = (const f4*)skb0;
    short* kh1w = kh1buf[w];
    float* pw = pbuf[w];
    const s8* K2f = (const s8*)fragK2;

    const int half = nbt >> 1;
    int gb = blockIdx.x;
    if (gb >= half) return;
    float pe[2][6]; int psi[2];
#pragma unroll
    for (int c = 0; c < 2; c++) {
        const int te = e0 + (gb + c * half) * 64 + w * 16 + cl;
        const float2* ep2 = reinterpret_cast<const float2*>(ea + (size_t)te * 6);
        float2 a = ep2[0], b = ep2[1], cc = ep2[2];
        pe[c][0] = a.x; pe[c][1] = a.y; pe[c][2] = b.x;
        pe[c][3] = b.y; pe[c][4] = cc.x; pe[c][5] = cc.y;
        psi[c] = src[te];
    }

    for (; gb < half; gb += gridDim.x) {
        int eb2[2];
        eb2[0] = gb * 64 + w * 16;
        eb2[1] = (gb + half) * 64 + w * 16;
        f4 xq2[2];
        float ce[2][6];
#pragma unroll
        for (int c = 0; c < 2; c++) {
            xq2[c] = *(const f4*)(xf0 + (size_t)psi[c] * 16 + g * 4);
#pragma unroll
            for (int k = 0; k < 6; k++) ce[c][k] = pe[c][k];
        }
        {
            int gn = gb + gridDim.x;
            if (gn > half - 1) gn = half - 1;
#pragma unroll
            for (int c = 0; c < 2; c++) {
                const int ten = e0 + (gn + c * half) * 64 + w * 16 + cl;
                const float2* ep2 = reinterpret_cast<const float2*>(ea + (size_t)ten * 6);
                float2 a = ep2[0], b = ep2[1], cc = ep2[2];
                pe[c][0] = a.x; pe[c][1] = a.y; pe[c][2] = b.x;
                pe[c][3] = b.y; pe[c][4] = cc.x; pe[c][5] = cc.y;
                psi[c] = src[ten];
            }
        }

        s8 a3s[2][2];
#pragma unroll
        for (int c = 0; c < 2; c++) {
            s8 a1[2];
#pragma unroll
            for (int s = 0; s < 2; s++) {
                f4 accA = KB04[8 * s + 2 * g];
                f4 accB = KB04[8 * s + 2 * g + 1];
#pragma unroll
                for (int f = 0; f < 6; f++) {
                    accA += ce[c][f] * K04[f * 16 + 8 * s + 2 * g];
                    accB += ce[c][f] * K04[f * 16 + 8 * s + 2 * g + 1];
                }
                s8 v;
#pragma unroll
                for (int jj = 0; jj < 4; jj++) v[jj] = f2b(fmaxf(accA[jj], 0.f));
#pragma unroll
                for (int jj = 0; jj < 4; jj++) v[4 + jj] = f2b(fmaxf(accB[jj], 0.f));
                a1[s] = v;
            }
#pragma unroll
            for (int n = 0; n < 4; n++) {
                f4 c2 = {0.f, 0.f, 0.f, 0.f};
                c2 = __builtin_amdgcn_mfma_f32_16x16x32_bf16(a1[0], K1B[0][n], c2, 0, 0, 0);
                c2 = __builtin_amdgcn_mfma_f32_16x16x32_bf16(a1[1], K1B[1][n], c2, 0, 0, 0);
#pragma unroll
                for (int r = 0; r < 4; r++) {
                    const int e = 4 * g + r;
                    const int byteoff = (e * 128 + (16 * n + cl) * 2) ^ ((e & 7) << 4);
                    *(short*)((char*)kh1w + byteoff) = f2b(fmaxf(c2[r] + b1v[n], 0.f));
                }
            }
#pragma unroll
            for (int s = 0; s < 2; s++) {
                const int byteoff = (cl * 128 + 64 * s + 16 * g) ^ ((cl & 7) << 4);
                a3s[c][s] = *(const s8*)((const char*)kh1w + byteoff);
            }
        }

#pragma unroll
        for (int c = 0; c < 2; c++) {
            f4 pv4;
#pragma unroll
            for (int n = 0; n < 16; n++) {
                f4 acc = *(const f4*)(sb2 + 16 * n + 4 * g);
                acc = __builtin_amdgcn_mfma_f32_16x16x32_bf16(K2f[(2 * n + 0) * 64 + lane], a3s[c][0], acc, 0, 0, 0);
                acc = __builtin_amdgcn_mfma_f32_16x16x32_bf16(K2f[(2 * n + 1) * 64 + lane], a3s[c][1], acc, 0, 0, 0);
                pv4[n & 3] = acc[0] * xq2[c][0] + acc[1] * xq2[c][1]
                           + acc[2] * xq2[c][2] + acc[3] * xq2[c][3];
                if ((n & 3) == 3) {
                    const int byteoff = (g * 1024 + cl * 64 + (n >> 2) * 16) ^ ((cl & 7) << 4);
                    *(f4*)((char*)pw + byteoff) = pv4;
                }
            }
            const int e16 = lane >> 2, q = lane & 3;
            f4 s0 = {0.f, 0.f, 0.f, 0.f};
#pragma unroll
            for (int gg = 0; gg < 4; gg++) {
                const int byteoff = (gg * 1024 + e16 * 64 + q * 16) ^ ((e16 & 7) << 4);
                f4 t = *(const f4*)((const char*)pw + byteoff);
                s0[0] += t[0]; s0[1] += t[1]; s0[2] += t[2]; s0[3] += t[3];
            }
            reinterpret_cast<f4*>(msgbuf)[(size_t)eb2[c] * 4 + lane] = s0;
        }
    }
}

// ---- Phase E2 (two-pass fallback only): segmented CSR reduction -> agg ----
__global__ void k_reduce(const float* __restrict__ msgbuf, const int* __restrict__ eidxp,
                         const int* __restrict__ basec, const int* __restrict__ cnt,
                         float* __restrict__ agg, int e0, int e1, int first) {
    int n = blockIdx.x * 256 + threadIdx.x;
    if (n >= NF) return;
    int c = cnt[n];
    int st = basec[n] - c;
    f4 a0, a1, a2, a3;
    if (first) {
        a0 = a1 = a2 = a3 = (f4){0.f, 0.f, 0.f, 0.f};
    } else {
        const f4* ap = (const f4*)(agg + (size_t)n * 16);
        a0 = ap[0]; a1 = ap[1]; a2 = ap[2]; a3 = ap[3];
    }
    for (int j = 0; j < c; j++) {
        int eid = eidxp[st + j];
        if (eid < e0 || eid >= e1) continue;
        const f4* mp = (const f4*)(msgbuf + (size_t)(eid - e0) * 16);
        a0 += mp[0]; a1 += mp[1]; a2 += mp[2]; a3 += mp[3];
    }
    f4* op = (f4*)(agg + (size_t)n * 16);
    op[0] = a0; op[1] = a1; op[2] = a2; op[3] = a3;
}

// ---- Phase F: fused msg reduce + root + online-softmax attention + FiLM + dec ----
__global__ void __launch_bounds__(256, 1) k_final(
        const float* __restrict__ xf0, const float* __restrict__ agg,
        const float* __restrict__ msgbuf, const int* __restrict__ eidxp,
        const int* __restrict__ basec,
        const int* __restrict__ cnt, const int* __restrict__ cnt2,
        const int* __restrict__ base2c, const int* __restrict__ eidx2,
        const int* __restrict__ src_mf, const float* __restrict__ ea,
        const float* __restrict__ knode, const float* __restrict__ vnode,
        const float* __restrict__ misc,
        const float* __restrict__ Wq, const float* __restrict__ We,
        const float* __restrict__ Wr, const float* __restrict__ br,
        const float* __restrict__ dW, const float* __restrict__ db,
        float* __restrict__ out, int fuseReduce) {
    __shared__ float sWr[256], sWq[256], sWe[96], sbr[16], ssc[16], ssh[16], sD[48], sdb[3];
    int tid = threadIdx.x;
    for (int i = tid; i < 256; i += 256) { sWr[i] = Wr[i]; sWq[i] = Wq[i]; }
    if (tid < 96) sWe[tid] = We[tid];
    if (tid < 16) { sbr[tid] = br[tid]; ssc[tid] = misc[16 + tid]; ssh[tid] = misc[32 + tid]; }
    if (tid < 48) sD[tid] = dW[tid];
    if (tid < 3) sdb[tid] = db[tid];
    __syncthreads();
    int n = blockIdx.x * 256 + tid;
    if (n >= NF) return;
    int c = cnt[n];
    f4 a0, a1, a2, a3;
    if (fuseReduce) {
        a0 = a1 = a2 = a3 = (f4){0.f, 0.f, 0.f, 0.f};
        int st = basec[n] - c;
        if (c > 0) {
            int eid = eidxp[st];
            for (int j = 0; j < c; j++) {
                int eidn = eid;
                if (j + 1 < c) eidn = eidxp[st + j + 1];
                const f4* mp = (const f4*)(msgbuf + (size_t)eid * 16);
                a0 += mp[0]; a1 += mp[1]; a2 += mp[2]; a3 += mp[3];
                eid = eidn;
            }
        }
    } else {
        const f4* ap = (const f4*)(agg + (size_t)n * 16);
        a0 = ap[0]; a1 = ap[1]; a2 = ap[2]; a3 = ap[3];
    }
    float f[16];
#pragma unroll
    for (int q = 0; q < 4; q++) {
        float4 v = reinterpret_cast<const float4*>(xf0)[n * 4 + q];
        f[4 * q] = v.x; f[4 * q + 1] = v.y; f[4 * q + 2] = v.z; f[4 * q + 3] = v.w;
    }
    float r[16], qv[16];
#pragma unroll
    for (int cc = 0; cc < 16; cc++) {
        float ar = sbr[cc], aq = 0.f;
#pragma unroll
        for (int i = 0; i < 16; i++) { ar += f[i] * sWr[i * 16 + cc]; aq += f[i] * sWq[i * 16 + cc]; }
        r[cc] = ar; qv[cc] = aq;
    }
    float num[16];
#pragma unroll
    for (int i = 0; i < 16; i++) num[i] = 0.f;
    float den = 0.f, m = -3.0e38f;
    int c2 = cnt2[n];
    int st2 = base2c[n] - c2;
    if (c2 > 0) {
        int eid = eidx2[st2];
        int s = src_mf[eid];
        for (int j = 0; j < c2; j++) {
            int eidn = eid, sn = s;
            if (j + 1 < c2) { eidn = eidx2[st2 + j + 1]; sn = src_mf[eidn]; }
            const float2* ep = reinterpret_cast<const float2*>(ea + (size_t)eid * 6);
            float2 e01 = ep[0], e23 = ep[1], e45 = ep[2];
            float sc = 0.f;
#pragma unroll
            for (int q4i = 0; q4i < 4; q4i++) {
                float4 k4 = reinterpret_cast<const float4*>(knode)[(size_t)s * 4 + q4i];
                float kk[4] = {k4.x, k4.y, k4.z, k4.w};
#pragma unroll
                for (int jj = 0; jj < 4; jj++) {
                    int cc = 4 * q4i + jj;
                    kk[jj] += e01.x * sWe[cc] + e01.y * sWe[16 + cc] + e23.x * sWe[32 + cc]
                            + e23.y * sWe[48 + cc] + e45.x * sWe[64 + cc] + e45.y * sWe[80 + cc];
                    sc += qv[cc] * kk[jj];
                }
            }
            sc *= 0.25f;
            if (sc > m) {
                float rs = expf(m - sc);
                den *= rs;
#pragma unroll
                for (int i = 0; i < 16; i++) num[i] *= rs;
                m = sc;
            }
            float e = expf(sc - m);
            den += e;
#pragma unroll
            for (int q4i = 0; q4i < 4; q4i++) {
                float4 v4 = reinterpret_cast<const float4*>(vnode)[(size_t)s * 4 + q4i];
                num[4 * q4i + 0] += e * v4.x;
                num[4 * q4i + 1] += e * v4.y;
                num[4 * q4i + 2] += e * v4.z;
                num[4 * q4i + 3] += e * v4.w;
            }
            eid = eidn; s = sn;
        }
    }
    float rdn = 1.0f / (den + 1e-16f);
    float rdg = 1.0f / fmaxf((float)c, 1.0f);
    float xo[16];
#pragma unroll
    for (int q = 0; q < 4; q++) {
        f4 a4 = (q == 0) ? a0 : (q == 1) ? a1 : (q == 2) ? a2 : a3;
#pragma unroll
        for (int jj = 0; jj < 4; jj++) {
            int cc = 4 * q + jj;
            float v = r[cc] + a4[jj] * rdg + num[cc] * rdn;
            float rr = fmaxf(v, 0.f);
            xo[cc] = rr + (rr * ssc[cc] + ssh[cc]);
        }
    }
#pragma unroll
    for (int k = 0; k < 3; k++) {
        float acc = sdb[k];
#pragma unroll
        for (int i = 0; i < 16; i++) acc += xo[i] * sD[i * 3 + k];
        out[n * 3 + k] = acc;
    }
}

extern "C" void kernel_launch(void* const* d_in, const int* in_sizes, int n_in,
                              void* d_out, int out_size, void* d_ws, size_t ws_size,
                              hipStream_t stream) {
    const float* flow_x   = (const float*)d_in[0];
    const float* memb_y   = (const float*)d_in[1];
    const float* tau      = (const float*)d_in[2];
    const float* ea_ff    = (const float*)d_in[3];
    const float* ea_mf    = (const float*)d_in[4];
    const float* enc_f_W  = (const float*)d_in[5];
    const float* enc_f_b  = (const float*)d_in[6];
    const float* enc_m_W1 = (const float*)d_in[7];
    const float* enc_m_b1 = (const float*)d_in[8];
    const float* enc_m_W2 = (const float*)d_in[9];
    const float* enc_m_b2 = (const float*)d_in[10];
    const float* K0       = (const float*)d_in[11];
    const float* kb0      = (const float*)d_in[12];
    const float* K1       = (const float*)d_in[13];
    const float* kb1      = (const float*)d_in[14];
    const float* K2       = (const float*)d_in[15];
    const float* kb2      = (const float*)d_in[16];
    const float* W_root   = (const float*)d_in[17];
    const float* b_root   = (const float*)d_in[18];
    const float* Wq       = (const float*)d_in[19];
    const float* Wk       = (const float*)d_in[20];
    const float* We       = (const float*)d_in[21];
    const float* Wv       = (const float*)d_in[22];
    const float* tc_W1    = (const float*)d_in[23];
    const float* tc_b1    = (const float*)d_in[24];
    const float* tc_W2    = (const float*)d_in[25];
    const float* tc_b2    = (const float*)d_in[26];
    const float* dec_f_W  = (const float*)d_in[27];
    const float* dec_f_b  = (const float*)d_in[28];
    const float* dec_m_W  = (const float*)d_in[29];
    const float* dec_m_b  = (const float*)d_in[30];
    const int* src_ff = (const int*)d_in[31];
    const int* dst_ff = (const int*)d_in[32];
    const int* src_mf = (const int*)d_in[33];
    const int* dst_mf = (const int*)d_in[34];

    float* out = (float*)d_out;
    float* ws = (float*)d_ws;

    // fixed region: 2,960,576 elems = 11.84 MB
    float* misc  = ws;                           // 64
    float* knode = ws + 64;                      // NM*16
    float* vnode = knode + (size_t)NM * 16;      // NM*16
    float* xf0   = vnode + (size_t)NM * 16;      // NF*16
    float* agg   = xf0 + (size_t)NF * 16;        // NF*16 (two-pass fallback only)
    int* cnt    = (int*)(agg + (size_t)NF * 16); // NF    (zeroed)
    int* cnt2   = cnt + NF;                      // NF    (zeroed)
    int* base   = cnt2 + NF;                     // NF
    int* base2  = base + NF;                     // NF
    int* eidxp  = base2 + NF;                    // EFF
    int* eidx2  = eidxp + EFF;                   // EMF
    int* bsA    = eidx2 + EMF;                   // 256
    int* bsB    = bsA + 256;                     // 256
    float* msgbuf = (float*)(bsB + 256);         // EH*16 floats

    // single-pass needs 63.05 MB (proven: r7-r17 ran single-pass); fallback 37.4 MB
    const int npass = (ws_size >= 63100000ULL) ? 1 : 2;
    const int EH = EFF / npass;

    hipMemsetAsync(cnt, 0, 2 * (size_t)NF * sizeof(int), stream);

    k_prep<<<FB + MB + 1 + HB, 256, 0, stream>>>(
        flow_x, memb_y, tau, enc_f_W, enc_f_b, enc_m_W1, enc_m_b1, enc_m_W2, enc_m_b2,
        dec_m_W, dec_m_b, Wk, Wv, tc_W1, tc_b1, tc_W2, tc_b2, dst_ff, dst_mf,
        xf0, knode, vnode, out + (size_t)NF * 3, misc, cnt, cnt2);
    k_scanA2<<<2 * FB, 256, 0, stream>>>(cnt, cnt2, bsA, bsB);
    k_scanC2<<<2 * FB, 256, 0, stream>>>(cnt, cnt2, bsA, bsB, base, base2);
    k_scatter<<<HB, 256, 0, stream>>>(dst_ff, dst_mf, base, base2, eidxp, eidx2);
    if (npass == 1) {
        k_edge_msg<<<512, 256, 0, stream>>>(ea_ff, src_ff, K0, kb0, K1, kb1, K2, kb2,
                                            xf0, msgbuf, 0, EFF / 64);
        k_final<<<FB, 256, 0, stream>>>(xf0, agg, msgbuf, eidxp, base, cnt, cnt2,
                                        base2, eidx2, src_mf, ea_mf, knode, vnode, misc,
                                        Wq, We, W_root, b_root, dec_f_W, dec_f_b, out, 1);
    } else {
        for (int p = 0; p < npass; p++) {
            k_edge_msg<<<512, 256, 0, stream>>>(ea_ff, src_ff, K0, kb0, K1, kb1, K2, kb2,
                                                xf0, msgbuf, p * EH, EH / 64);
            k_reduce<<<FB, 256, 0, stream>>>(msgbuf, eidxp, base, cnt, agg,
                                             p * EH, (p + 1) * EH, p == 0);
        }
        k_final<<<FB, 256, 0, stream>>>(xf0, agg, msgbuf, eidxp, base, cnt, cnt2,
                                        base2, eidx2, src_mf, ea_mf, knode, vnode, misc,
                                        Wq, We, W_root, b_root, dec_f_W, dec_f_b, out, 0);
    }
}